// Round 3
// baseline (1246.727 us; speedup 1.0000x reference)
//
#include <hip/hip_runtime.h>
#include <hip/hip_bf16.h>
#include <stdint.h>
#include <stddef.h>

// CrossModalAttentionBlock on MI355X.
// Softmax over a single key == 1, so the attention collapses:
//   a_attn = e_b @ (w_out_ab @ wv_ab)^T + (w_out_ab @ bv_ab + b_out_ab)
//   b_attn = e_a @ (w_out_ba @ wv_ba)^T + (w_out_ba @ bv_ba + b_out_ba)
//   attn_w = 1.0 exactly.
// Then e_a' = LN(e_a + a_attn), e_b' = LN(e_b + b_attn).
// Main GEMMs run in bf16 via mfma_f32_16x16x32_bf16 (m97 128^2 structure).

static constexpr int B_ROWS = 16384;
static constexpr int DIM    = 2048;
static constexpr float EPS  = 1e-5f;

typedef __bf16 bf16_t;
typedef __bf16 bf16x8 __attribute__((ext_vector_type(8)));
typedef float  f32x4  __attribute__((ext_vector_type(4)));

// ---------------- fp32 -> bf16 convert (8 elems/thread, 32B read/16B write) ----
__global__ __launch_bounds__(256) void k_f32_to_bf16(const float* __restrict__ in,
                                                     bf16_t* __restrict__ out) {
  size_t i = ((size_t)blockIdx.x * 256 + threadIdx.x) * 8;
  f32x4 a = *(const f32x4*)(in + i);
  f32x4 b = *(const f32x4*)(in + i + 4);
  bf16x8 o;
  o[0] = (bf16_t)a[0]; o[1] = (bf16_t)a[1]; o[2] = (bf16_t)a[2]; o[3] = (bf16_t)a[3];
  o[4] = (bf16_t)b[0]; o[5] = (bf16_t)b[1]; o[6] = (bf16_t)b[2]; o[7] = (bf16_t)b[3];
  *(bf16x8*)(out + i) = o;
}

// ---------------- fp32 -> bf16 transposed copy (for Wv -> Wv^T) ---------------
__global__ __launch_bounds__(256) void k_transpose_bf16(const float* __restrict__ W,
                                                        bf16_t* __restrict__ Wt,
                                                        int n) {
  __shared__ float t[32][33];
  const int bx = blockIdx.x * 32, by = blockIdx.y * 32;
  const int tx = threadIdx.x & 31, ty = threadIdx.x >> 5;
  #pragma unroll
  for (int r = ty; r < 32; r += 8)
    t[r][tx] = W[(size_t)(by + r) * n + bx + tx];
  __syncthreads();
  #pragma unroll
  for (int r = ty; r < 32; r += 8)
    Wt[(size_t)(bx + r) * n + by + tx] = (bf16_t)t[tx][r];
}

// ---------------- combined bias: bc[i] = sum_k w_out[i,k]*bv[k] + b_out[i] ----
__global__ __launch_bounds__(256) void k_bias_combine(const float* __restrict__ wout,
                                                      const float* __restrict__ bv,
                                                      const float* __restrict__ bout,
                                                      float* __restrict__ bc, int n) {
  const int i = blockIdx.x;
  const float* row = wout + (size_t)i * n;
  float s = 0.f;
  for (int k = threadIdx.x; k < n; k += 256) s += row[k] * bv[k];
  #pragma unroll
  for (int o = 32; o; o >>= 1) s += __shfl_down(s, o, 64);
  __shared__ float red[4];
  if ((threadIdx.x & 63) == 0) red[threadIdx.x >> 6] = s;
  __syncthreads();
  if (threadIdx.x == 0) bc[i] = red[0] + red[1] + red[2] + red[3] + bout[i];
}

// ---------------- MFMA GEMM, C[m,n] = sum_k A[m,k] * Bt[n,k] ------------------
// m97 structure: 128x128 tile, BK=32, 4 waves (2x2), 16x16x32 bf16 MFMA,
// global_load_lds width 16, 2 barriers per K-step.
// MODE 0: write bf16 C (weight-combine GEMM).
// MODE 1: write fp32 C + residual + bias (main GEMM; output feeds LayerNorm).
//         MODE 1 also applies a bijective XCD swizzle to the block id.
__device__ inline void gld_lds16(const bf16_t* g, bf16_t* l) {
  __builtin_amdgcn_global_load_lds(
      (const __attribute__((address_space(1))) void*)g,
      (__attribute__((address_space(3))) void*)l, 16, 0, 0);
}

template <int MODE>
__global__ __launch_bounds__(256) void k_gemm_bt(const bf16_t* __restrict__ A,
                                                 const bf16_t* __restrict__ Bt,
                                                 float* __restrict__ Cf,
                                                 bf16_t* __restrict__ Cb,
                                                 const float* __restrict__ resid,
                                                 const float* __restrict__ bias,
                                                 int M, int N, int K) {
  __shared__ bf16_t lA[128 * 32];
  __shared__ bf16_t lB[128 * 32];
  const int tid  = threadIdx.x;
  const int lane = tid & 63;
  const int wid  = tid >> 6;
  const int wm = wid >> 1, wn = wid & 1;      // 2x2 wave grid, 64x64 each

  // Block-id -> tile mapping. MODE 1: XCD-aware swizzle (nwg % 8 == 0 here,
  // so orig%8 / orig/8 is bijective).
  int bx, by;
  if (MODE == 1) {
    const int nbx = N >> 7;
    const int nwg = (M >> 7) * nbx;
    const int orig = blockIdx.y * nbx + blockIdx.x;
    const int cpx = nwg >> 3;
    const int swz = (orig & 7) * cpx + (orig >> 3);
    bx = swz % nbx;
    by = swz / nbx;
  } else {
    bx = blockIdx.x;
    by = blockIdx.y;
  }
  const int m0 = by * 128, n0 = bx * 128;

  // Staging: tile is row-major [128][32] bf16 (64B per row => 4 lanes per row).
  const int sr = tid >> 2;                    // staging row 0..63
  const int sc = (tid & 3) * 8;               // staging col {0,8,16,24}
  const bf16_t* gA0 = A  + (size_t)(m0 + sr) * K + sc;
  const bf16_t* gA1 = A  + (size_t)(m0 + 64 + sr) * K + sc;
  const bf16_t* gB0 = Bt + (size_t)(n0 + sr) * K + sc;
  const bf16_t* gB1 = Bt + (size_t)(n0 + 64 + sr) * K + sc;

  f32x4 acc[4][4] = {};

  const int fr = lane & 15;          // fragment row/col
  const int kh = (lane >> 4) * 8;    // k-slice base (8 contiguous bf16)

  for (int kt = 0; kt < K; kt += 32) {
    gld_lds16(gA0 + kt, lA + tid * 8);
    gld_lds16(gA1 + kt, lA + 2048 + tid * 8);
    gld_lds16(gB0 + kt, lB + tid * 8);
    gld_lds16(gB1 + kt, lB + 2048 + tid * 8);
    __syncthreads();   // compiler emits vmcnt(0) drain before barrier

    bf16x8 af[4], bfv[4];
    #pragma unroll
    for (int i = 0; i < 4; ++i) {
      af[i]  = *(const bf16x8*)(lA + (wm * 64 + i * 16 + fr) * 32 + kh);
      bfv[i] = *(const bf16x8*)(lB + (wn * 64 + i * 16 + fr) * 32 + kh);
    }
    #pragma unroll
    for (int i = 0; i < 4; ++i)
      #pragma unroll
      for (int j = 0; j < 4; ++j)
        acc[i][j] = __builtin_amdgcn_mfma_f32_16x16x32_bf16(af[i], bfv[j], acc[i][j], 0, 0, 0);
    __syncthreads();   // protect LDS before next stage
  }

  // Epilogue. C/D layout (m89-verified): col = lane&15, row = (lane>>4)*4 + reg.
  const int cr = (lane >> 4) * 4;
  const int cc = lane & 15;
  #pragma unroll
  for (int i = 0; i < 4; ++i) {
    #pragma unroll
    for (int j = 0; j < 4; ++j) {
      const int gm = m0 + wm * 64 + i * 16 + cr;
      const int gn = n0 + wn * 64 + j * 16 + cc;
      #pragma unroll
      for (int r = 0; r < 4; ++r) {
        const size_t idx = (size_t)(gm + r) * N + gn;
        if (MODE == 0) {
          Cb[idx] = (bf16_t)acc[i][j][r];
        } else {
          Cf[idx] = acc[i][j][r] + resid[idx] + bias[gn];
        }
      }
    }
  }
}

// ---------------- in-place LayerNorm over the last dim (row = 2048) -----------
__global__ __launch_bounds__(256) void k_ln(float* __restrict__ io,
                                            const float* __restrict__ gamma_a,
                                            const float* __restrict__ beta_a,
                                            const float* __restrict__ gamma_b,
                                            const float* __restrict__ beta_b) {
  const int row = blockIdx.x;
  const float* gamma = (row < B_ROWS) ? gamma_a : gamma_b;
  const float* beta  = (row < B_ROWS) ? beta_a  : beta_b;
  float* p = io + (size_t)row * DIM;
  const int c0 = threadIdx.x * 8;

  f32x4 x0 = *(f32x4*)(p + c0);
  f32x4 x1 = *(f32x4*)(p + c0 + 4);
  float s = 0.f, sq = 0.f;
  #pragma unroll
  for (int r = 0; r < 4; ++r) {
    s += x0[r] + x1[r];
    sq += x0[r] * x0[r] + x1[r] * x1[r];
  }
  #pragma unroll
  for (int o = 32; o; o >>= 1) {
    s  += __shfl_down(s, o, 64);
    sq += __shfl_down(sq, o, 64);
  }
  __shared__ float rs[4], rq[4];
  if ((threadIdx.x & 63) == 0) { rs[threadIdx.x >> 6] = s; rq[threadIdx.x >> 6] = sq; }
  __syncthreads();
  s  = rs[0] + rs[1] + rs[2] + rs[3];
  sq = rq[0] + rq[1] + rq[2] + rq[3];

  const float mean = s * (1.f / DIM);
  const float var  = sq * (1.f / DIM) - mean * mean;
  const float inv  = rsqrtf(var + EPS);

  f32x4 g0 = *(const f32x4*)(gamma + c0);
  f32x4 g1 = *(const f32x4*)(gamma + c0 + 4);
  f32x4 b0 = *(const f32x4*)(beta + c0);
  f32x4 b1 = *(const f32x4*)(beta + c0 + 4);
  #pragma unroll
  for (int r = 0; r < 4; ++r) {
    x0[r] = (x0[r] - mean) * inv * g0[r] + b0[r];
    x1[r] = (x1[r] - mean) * inv * g1[r] + b1[r];
  }
  *(f32x4*)(p + c0)     = x0;
  *(f32x4*)(p + c0 + 4) = x1;
}

// ---------------- attn_w == 1.0 exactly ---------------------------------------
__global__ __launch_bounds__(256) void k_fill_ones(float* __restrict__ p, int n) {
  const int i = blockIdx.x * 256 + threadIdx.x;
  if (i < n) p[i] = 1.0f;
}

extern "C" void kernel_launch(void* const* d_in, const int* in_sizes, int n_in,
                              void* d_out, int out_size, void* d_ws, size_t ws_size,
                              hipStream_t stream) {
  const float* e_a      = (const float*)d_in[0];
  const float* e_b      = (const float*)d_in[1];
  const float* w_in_ab  = (const float*)d_in[2];
  const float* b_in_ab  = (const float*)d_in[3];
  const float* w_out_ab = (const float*)d_in[4];
  const float* b_out_ab = (const float*)d_in[5];
  const float* w_in_ba  = (const float*)d_in[6];
  const float* b_in_ba  = (const float*)d_in[7];
  const float* w_out_ba = (const float*)d_in[8];
  const float* b_out_ba = (const float*)d_in[9];
  const float* gamma_a  = (const float*)d_in[10];
  const float* beta_a   = (const float*)d_in[11];
  const float* gamma_b  = (const float*)d_in[12];
  const float* beta_b   = (const float*)d_in[13];
  float* out = (float*)d_out;

  // Workspace carve-up (~185 MB total).
  char* w = (char*)d_ws;
  bf16_t* eA_bf  = (bf16_t*)w; w += (size_t)B_ROWS * DIM * 2;
  bf16_t* eB_bf  = (bf16_t*)w; w += (size_t)B_ROWS * DIM * 2;
  bf16_t* woAB   = (bf16_t*)w; w += (size_t)DIM * DIM * 2;
  bf16_t* woBA   = (bf16_t*)w; w += (size_t)DIM * DIM * 2;
  bf16_t* wvTAB  = (bf16_t*)w; w += (size_t)DIM * DIM * 2;
  bf16_t* wvTBA  = (bf16_t*)w; w += (size_t)DIM * DIM * 2;
  bf16_t* wcAB   = (bf16_t*)w; w += (size_t)DIM * DIM * 2;
  bf16_t* wcBA   = (bf16_t*)w; w += (size_t)DIM * DIM * 2;
  float*  bcAB   = (float*)w;  w += (size_t)DIM * 4;
  float*  bcBA   = (float*)w;  w += (size_t)DIM * 4;

  const size_t nE = (size_t)B_ROWS * DIM;   // 33,554,432
  const size_t nW = (size_t)DIM * DIM;      // 4,194,304

  // 1) dtype conversions
  k_f32_to_bf16<<<nE / 2048, 256, 0, stream>>>(e_a, eA_bf);
  k_f32_to_bf16<<<nE / 2048, 256, 0, stream>>>(e_b, eB_bf);
  k_f32_to_bf16<<<nW / 2048, 256, 0, stream>>>(w_out_ab, woAB);
  k_f32_to_bf16<<<nW / 2048, 256, 0, stream>>>(w_out_ba, woBA);
  // wv is rows [2D, 3D) of w_in; we need Wv^T (K-contiguous for the combine GEMM)
  k_transpose_bf16<<<dim3(64, 64), 256, 0, stream>>>(w_in_ab + 2 * nW, wvTAB, DIM);
  k_transpose_bf16<<<dim3(64, 64), 256, 0, stream>>>(w_in_ba + 2 * nW, wvTBA, DIM);
  // combined bias (fp32, exact)
  k_bias_combine<<<DIM, 256, 0, stream>>>(w_out_ab, b_in_ab + 2 * DIM, b_out_ab, bcAB, DIM);
  k_bias_combine<<<DIM, 256, 0, stream>>>(w_out_ba, b_in_ba + 2 * DIM, b_out_ba, bcBA, DIM);

  // 2) weight-combine GEMMs: Wc[i,j] = sum_k w_out[i,k] * wv[k,j]
  k_gemm_bt<0><<<dim3(16, 16), 256, 0, stream>>>(woAB, wvTAB, nullptr, wcAB,
                                                 nullptr, nullptr, DIM, DIM, DIM);
  k_gemm_bt<0><<<dim3(16, 16), 256, 0, stream>>>(woBA, wvTBA, nullptr, wcBA,
                                                 nullptr, nullptr, DIM, DIM, DIM);

  // 3) main GEMMs with fused residual + bias, fp32 out into d_out
  //    s_a = e_b @ WcAB^T + e_a + bcAB ; s_b = e_a @ WcBA^T + e_b + bcBA
  k_gemm_bt<1><<<dim3(16, 128), 256, 0, stream>>>(eB_bf, wcAB, out, nullptr,
                                                  e_a, bcAB, B_ROWS, DIM, DIM);
  k_gemm_bt<1><<<dim3(16, 128), 256, 0, stream>>>(eA_bf, wcBA, out + nE, nullptr,
                                                  e_b, bcBA, B_ROWS, DIM, DIM);

  // 4) in-place LayerNorm on both halves of d_out
  k_ln<<<2 * B_ROWS, 256, 0, stream>>>(out, gamma_a, beta_a, gamma_b, beta_b);

  // 5) attn_w output: exactly 1.0
  k_fill_ones<<<(B_ROWS + 255) / 256, 256, 0, stream>>>(out + 2 * nE, B_ROWS);
}

// Round 14
// 1070.876 us; speedup vs baseline: 1.1642x; 1.1642x over previous
//
#include <hip/hip_runtime.h>
#include <hip/hip_bf16.h>
#include <stdint.h>
#include <stddef.h>

// CrossModalAttentionBlock on MI355X.
// Softmax over a single key == 1, so the attention collapses:
//   a_attn = e_b @ (w_out_ab @ wv_ab)^T + (w_out_ab @ bv_ab + b_out_ab)
//   b_attn = e_a @ (w_out_ba @ wv_ba)^T + (w_out_ba @ bv_ba + b_out_ba)
//   attn_w = 1.0 exactly.
// Then e_a' = LN(e_a + a_attn), e_b' = LN(e_b + b_attn).
//
// Main GEMM: 256x256/BK=64/8-wave, 4-phase-per-K-tile schedule with counted
// vmcnt (T3+T4), setprio around MFMA (T5), XOR 16B-unit LDS swizzle compatible
// with global_load_lds (T2 via rule #21), raw s_barrier (NOT __syncthreads -
// that would drain vmcnt(0) and kill the pipeline), bijective XCD swizzle (T1).

static constexpr int B_ROWS = 16384;
static constexpr int DIM    = 2048;
static constexpr float EPS  = 1e-5f;

typedef __bf16 bf16_t;
typedef __bf16 bf16x8 __attribute__((ext_vector_type(8)));
typedef float  f32x4  __attribute__((ext_vector_type(4)));

#define MEMFENCE asm volatile("" ::: "memory")
#define SBAR     __builtin_amdgcn_s_barrier()
#define SCHEDB   __builtin_amdgcn_sched_barrier(0)
#define WAITVM(n) asm volatile("s_waitcnt vmcnt(" #n ")" ::: "memory")

__device__ __forceinline__ void gld_lds16(const bf16_t* g, bf16_t* l) {
  __builtin_amdgcn_global_load_lds(
      (const __attribute__((address_space(1))) void*)g,
      (__attribute__((address_space(3))) void*)l, 16, 0, 0);
}

// ---------------- fp32 -> bf16 convert (8 elems/thread) -----------------------
__global__ __launch_bounds__(256) void k_f32_to_bf16(const float* __restrict__ in,
                                                     bf16_t* __restrict__ out) {
  size_t i = ((size_t)blockIdx.x * 256 + threadIdx.x) * 8;
  f32x4 a = *(const f32x4*)(in + i);
  f32x4 b = *(const f32x4*)(in + i + 4);
  bf16x8 o;
  o[0] = (bf16_t)a[0]; o[1] = (bf16_t)a[1]; o[2] = (bf16_t)a[2]; o[3] = (bf16_t)a[3];
  o[4] = (bf16_t)b[0]; o[5] = (bf16_t)b[1]; o[6] = (bf16_t)b[2]; o[7] = (bf16_t)b[3];
  *(bf16x8*)(out + i) = o;
}

// ---------------- fp32 -> bf16 transposed copy (Wv -> Wv^T) -------------------
__global__ __launch_bounds__(256) void k_transpose_bf16(const float* __restrict__ W,
                                                        bf16_t* __restrict__ Wt,
                                                        int n) {
  __shared__ float t[32][33];
  const int bx = blockIdx.x * 32, by = blockIdx.y * 32;
  const int tx = threadIdx.x & 31, ty = threadIdx.x >> 5;
  #pragma unroll
  for (int r = ty; r < 32; r += 8)
    t[r][tx] = W[(size_t)(by + r) * n + bx + tx];
  __syncthreads();
  #pragma unroll
  for (int r = ty; r < 32; r += 8)
    Wt[(size_t)(bx + r) * n + by + tx] = (bf16_t)t[tx][r];
}

// ---------------- combined bias: bc[i] = sum_k w_out[i,k]*bv[k] + b_out[i] ----
__global__ __launch_bounds__(256) void k_bias_combine(const float* __restrict__ wout,
                                                      const float* __restrict__ bv,
                                                      const float* __restrict__ bout,
                                                      float* __restrict__ bc, int n) {
  const int i = blockIdx.x;
  const float* row = wout + (size_t)i * n;
  float s = 0.f;
  for (int k = threadIdx.x; k < n; k += 256) s += row[k] * bv[k];
  #pragma unroll
  for (int o = 32; o; o >>= 1) s += __shfl_down(s, o, 64);
  __shared__ float red[4];
  if ((threadIdx.x & 63) == 0) red[threadIdx.x >> 6] = s;
  __syncthreads();
  if (threadIdx.x == 0) bc[i] = red[0] + red[1] + red[2] + red[3] + bout[i];
}

// ---------------- small MFMA GEMM (m97 128^2), bf16 out, for weight-combine ---
__global__ __launch_bounds__(256) void k_gemm_bt_small(const bf16_t* __restrict__ A,
                                                       const bf16_t* __restrict__ Bt,
                                                       bf16_t* __restrict__ Cb,
                                                       int M, int N, int K) {
  __shared__ bf16_t lA[128 * 32];
  __shared__ bf16_t lB[128 * 32];
  const int tid  = threadIdx.x;
  const int lane = tid & 63;
  const int wid  = tid >> 6;
  const int wm = wid >> 1, wn = wid & 1;
  const int m0 = blockIdx.y * 128, n0 = blockIdx.x * 128;

  const int sr = tid >> 2;
  const int sc = (tid & 3) * 8;
  const bf16_t* gA0 = A  + (size_t)(m0 + sr) * K + sc;
  const bf16_t* gA1 = A  + (size_t)(m0 + 64 + sr) * K + sc;
  const bf16_t* gB0 = Bt + (size_t)(n0 + sr) * K + sc;
  const bf16_t* gB1 = Bt + (size_t)(n0 + 64 + sr) * K + sc;

  f32x4 acc[4][4] = {};
  const int fr = lane & 15;
  const int kh = (lane >> 4) * 8;

  for (int kt = 0; kt < K; kt += 32) {
    gld_lds16(gA0 + kt, lA + tid * 8);
    gld_lds16(gA1 + kt, lA + 2048 + tid * 8);
    gld_lds16(gB0 + kt, lB + tid * 8);
    gld_lds16(gB1 + kt, lB + 2048 + tid * 8);
    __syncthreads();
    bf16x8 af[4], bfv[4];
    #pragma unroll
    for (int i = 0; i < 4; ++i) {
      af[i]  = *(const bf16x8*)(lA + (wm * 64 + i * 16 + fr) * 32 + kh);
      bfv[i] = *(const bf16x8*)(lB + (wn * 64 + i * 16 + fr) * 32 + kh);
    }
    #pragma unroll
    for (int i = 0; i < 4; ++i)
      #pragma unroll
      for (int j = 0; j < 4; ++j)
        acc[i][j] = __builtin_amdgcn_mfma_f32_16x16x32_bf16(af[i], bfv[j], acc[i][j], 0, 0, 0);
    __syncthreads();
  }
  const int cr = (lane >> 4) * 4;
  const int cc = lane & 15;
  #pragma unroll
  for (int i = 0; i < 4; ++i)
    #pragma unroll
    for (int j = 0; j < 4; ++j) {
      const int gm = m0 + wm * 64 + i * 16 + cr;
      const int gn = n0 + wn * 64 + j * 16 + cc;
      #pragma unroll
      for (int r = 0; r < 4; ++r)
        Cb[(size_t)(gm + r) * N + gn] = (bf16_t)acc[i][j][r];
    }
}

// ---------------- MAIN GEMM: 256^2 tile, BK=64, 8 waves, counted-vmcnt --------
// C[m,n] = sum_k A[m,k]*Bt[n,k]; writes fp32 C + resid + bias.
//
// LDS: lA/lB[2][256][64] bf16 (128 KiB). 16B-unit XOR swizzle: unit u of row r
// stores global unit u^(r&7) (involution; staging pre-permutes the GLOBAL
// source per rule #21, LDS dest stays linear for global_load_lds).
//
// Per K-tile: 4 phases (mg,kk) = (0,0),(1,0),(0,1),(1,1); each: ds_read frags,
// 2 gld_lds staging next tile, s_barrier, 16 MFMA in setprio(1), s_barrier.
// Staging order: ph0:B0,B1  ph1:B2,B3  ph2:A0,A2  ph3:A1,A3  (chunk = 64 rows).
// Consumption: ph0 of tile t needs B(all)+A{0,2}; ph1 needs A{1,3}.
//  -> vmcnt(2) at end-ph0 (A1,A3 of THIS tile were the last 2 loads of the
//     previous tile's ph3) and at end-ph3 (leave next tile's A1,A3 in flight).
//  Never vmcnt(0) in the main loop; last tile peeled with vmcnt(0) at end-ph0.
__global__ __launch_bounds__(512, 2) void k_gemm256(const bf16_t* __restrict__ A,
                                                    const bf16_t* __restrict__ Bt,
                                                    float* __restrict__ Cf,
                                                    const float* __restrict__ resid,
                                                    const float* __restrict__ bias,
                                                    int M, int N, int K) {
  __shared__ bf16_t lA[2][256 * 64];
  __shared__ bf16_t lB[2][256 * 64];
  const int tid  = threadIdx.x;
  const int lane = tid & 63;
  const int wid  = tid >> 6;
  const int wr = wid >> 2;          // 0..1  (128 output rows each)
  const int wc = wid & 3;           // 0..3  (64 output cols each)

  // T1: bijective XCD swizzle (nwg multiple of 8: 64*8=512 here).
  const int nbx = N >> 8;
  const int nwg = (M >> 8) * nbx;
  const int orig = blockIdx.y * nbx + blockIdx.x;
  const int cpx = nwg >> 3;
  const int swz = (orig & 7) * cpx + (orig >> 3);
  const int m0 = (swz / nbx) << 8;
  const int n0 = (swz % nbx) << 8;

  // Staging map: thread t covers LDS bytes chunk*8192 + t*16 (linear dest).
  // LDS (row = chunk*64 + t/8, unit u_lin = t&7) must hold global unit
  // u_g = u_lin ^ (row&7) = (t&7) ^ ((t>>3)&7)  (chunk*64 == 0 mod 8).
  const int srow  = tid >> 3;                       // 0..63 within chunk
  const int sunit = (tid & 7) ^ ((tid >> 3) & 7);   // pre-permuted global unit
  const bf16_t* gA = A  + (size_t)(m0 + srow) * K + sunit * 8;
  const bf16_t* gB = Bt + (size_t)(n0 + srow) * K + sunit * 8;
  const size_t cK = (size_t)64 * K;                 // chunk row stride in elems
  const int lofs = tid * 8;                         // within-chunk LDS elems

  f32x4 acc[8][4] = {};

  const int NT = K >> 6;            // K-tiles of 64

  // ds_read fragment address helper (swizzled read, matches staging involution)
  // A-frag i (0..7), kk (0..1): row = wr*128+i*16+(lane&15); unit su =
  // (kk*4+(lane>>4)) ^ (lane&7)  [row&7 == lane&7 since bases are mult of 8].
  const int frl = lane & 15;
  const int fxor = lane & 7;
  const int fg  = lane >> 4;

#define LDA(buf, i, kk) \
  (*(const bf16x8*)(&lA[buf][(wr * 128 + (i) * 16 + frl) * 64 + \
                            ((((kk) * 4 + fg) ^ fxor) * 8)]))
#define LDB(buf, j, kk) \
  (*(const bf16x8*)(&lB[buf][(wc * 64 + (j) * 16 + frl) * 64 + \
                            ((((kk) * 4 + fg) ^ fxor) * 8)]))
#define STAGE_A(buf, c, kt) gld_lds16(gA + (size_t)(c) * cK + (kt), \
                                      &lA[buf][(c) * 4096 + lofs])
#define STAGE_B(buf, c, kt) gld_lds16(gB + (size_t)(c) * cK + (kt), \
                                      &lB[buf][(c) * 4096 + lofs])

#define MFMA16(mg, kk)                                                         \
  __builtin_amdgcn_s_setprio(1);                                               \
  _Pragma("unroll")                                                            \
  for (int mi = 0; mi < 4; ++mi) {                                             \
    _Pragma("unroll")                                                          \
    for (int j = 0; j < 4; ++j)                                                \
      acc[(mg) * 4 + mi][j] = __builtin_amdgcn_mfma_f32_16x16x32_bf16(         \
          af[mi], bf[j], acc[(mg) * 4 + mi][j], 0, 0, 0);                      \
  }                                                                            \
  __builtin_amdgcn_s_setprio(0)

  // ---- prologue: fully stage tile 0 into buf 0, drain, barrier --------------
  {
    STAGE_B(0, 0, 0); STAGE_B(0, 1, 0); STAGE_B(0, 2, 0); STAGE_B(0, 3, 0);
    STAGE_A(0, 0, 0); STAGE_A(0, 2, 0); STAGE_A(0, 1, 0); STAGE_A(0, 3, 0);
    WAITVM(0); SCHEDB;
    MEMFENCE; SBAR; MEMFENCE;
  }

  bf16x8 bf[4];
  int buf = 0;

  // ---- main loop: tiles 0 .. NT-2, staging tile t+1 into buf^1 --------------
  for (int t = 0; t < NT - 1; ++t) {
    const int ktn = (t + 1) << 6;   // next tile's k-offset (elements)
    const int nb = buf ^ 1;
    // ---- ph0: (mg0, kk0) ----
    {
      bf16x8 af[4];
      #pragma unroll
      for (int mi = 0; mi < 4; ++mi) af[mi] = LDA(buf, mi, 0);
      #pragma unroll
      for (int j = 0; j < 4; ++j) bf[j] = LDB(buf, j, 0);
      STAGE_B(nb, 0, ktn); STAGE_B(nb, 1, ktn);
      MEMFENCE; SBAR; MEMFENCE;
      MFMA16(0, 0);
      WAITVM(2); SCHEDB;            // A1,A3 of THIS tile land; B0',B1' fly
      MEMFENCE; SBAR; MEMFENCE;
    }
    // ---- ph1: (mg1, kk0) ----
    {
      bf16x8 af[4];
      #pragma unroll
      for (int mi = 0; mi < 4; ++mi) af[mi] = LDA(buf, 4 + mi, 0);
      STAGE_B(nb, 2, ktn); STAGE_B(nb, 3, ktn);
      MEMFENCE; SBAR; MEMFENCE;
      MFMA16(1, 0);
      MEMFENCE; SBAR; MEMFENCE;
    }
    // ---- ph2: (mg0, kk1) ----
    {
      bf16x8 af[4];
      #pragma unroll
      for (int mi = 0; mi < 4; ++mi) af[mi] = LDA(buf, mi, 1);
      #pragma unroll
      for (int j = 0; j < 4; ++j) bf[j] = LDB(buf, j, 1);
      STAGE_A(nb, 0, ktn); STAGE_A(nb, 2, ktn);
      MEMFENCE; SBAR; MEMFENCE;
      MFMA16(0, 1);
      MEMFENCE; SBAR; MEMFENCE;
    }
    // ---- ph3: (mg1, kk1) ----
    {
      bf16x8 af[4];
      #pragma unroll
      for (int mi = 0; mi < 4; ++mi) af[mi] = LDA(buf, 4 + mi, 1);
      STAGE_A(nb, 1, ktn); STAGE_A(nb, 3, ktn);
      MEMFENCE; SBAR; MEMFENCE;
      MFMA16(1, 1);
      WAITVM(2); SCHEDB;            // all but A1',A3' landed for next tile ph0
      MEMFENCE; SBAR; MEMFENCE;
    }
    buf = nb;
  }

  // ---- peeled last tile (no staging; vmcnt(0) before reading A chunks 1,3) --
  {
    {
      bf16x8 af[4];
      #pragma unroll
      for (int mi = 0; mi < 4; ++mi) af[mi] = LDA(buf, mi, 0);
      #pragma unroll
      for (int j = 0; j < 4; ++j) bf[j] = LDB(buf, j, 0);
      MEMFENCE; SBAR; MEMFENCE;
      MFMA16(0, 0);
      WAITVM(0); SCHEDB;            // only A1,A3 of this tile can be in flight
      MEMFENCE; SBAR; MEMFENCE;
    }
    {
      bf16x8 af[4];
      #pragma unroll
      for (int mi = 0; mi < 4; ++mi) af[mi] = LDA(buf, 4 + mi, 0);
      MEMFENCE; SBAR; MEMFENCE;
      MFMA16(1, 0);
      MEMFENCE; SBAR; MEMFENCE;
    }
    {
      bf16x8 af[4];
      #pragma unroll
      for (int mi = 0; mi < 4; ++mi) af[mi] = LDA(buf, mi, 1);
      #pragma unroll
      for (int j = 0; j < 4; ++j) bf[j] = LDB(buf, j, 1);
      MEMFENCE; SBAR; MEMFENCE;
      MFMA16(0, 1);
      MEMFENCE; SBAR; MEMFENCE;
    }
    {
      bf16x8 af[4];
      #pragma unroll
      for (int mi = 0; mi < 4; ++mi) af[mi] = LDA(buf, 4 + mi, 1);
      MEMFENCE; SBAR; MEMFENCE;
      MFMA16(1, 1);
    }
  }

  // ---- epilogue: C = acc + resid + bias (fp32), m89-verified C/D layout -----
  const int cr = (lane >> 4) * 4;
  const int cc = lane & 15;
  #pragma unroll
  for (int i = 0; i < 8; ++i) {
    #pragma unroll
    for (int j = 0; j < 4; ++j) {
      const int gm = m0 + wr * 128 + i * 16 + cr;
      const int gn = n0 + wc * 64 + j * 16 + cc;
      #pragma unroll
      for (int r = 0; r < 4; ++r) {
        const size_t idx = (size_t)(gm + r) * N + gn;
        Cf[idx] = acc[i][j][r] + resid[idx] + bias[gn];
      }
    }
  }
#undef LDA
#undef LDB
#undef STAGE_A
#undef STAGE_B
#undef MFMA16
}

// ---------------- in-place LayerNorm over the last dim (row = 2048) -----------
__global__ __launch_bounds__(256) void k_ln(float* __restrict__ io,
                                            const float* __restrict__ gamma_a,
                                            const float* __restrict__ beta_a,
                                            const float* __restrict__ gamma_b,
                                            const float* __restrict__ beta_b) {
  const int row = blockIdx.x;
  const float* gamma = (row < B_ROWS) ? gamma_a : gamma_b;
  const float* beta  = (row < B_ROWS) ? beta_a  : beta_b;
  float* p = io + (size_t)row * DIM;
  const int c0 = threadIdx.x * 8;

  f32x4 x0 = *(f32x4*)(p + c0);
  f32x4 x1 = *(f32x4*)(p + c0 + 4);
  float s = 0.f, sq = 0.f;
  #pragma unroll
  for (int r = 0; r < 4; ++r) {
    s += x0[r] + x1[r];
    sq += x0[r] * x0[r] + x1[r] * x1[r];
  }
  #pragma unroll
  for (int o = 32; o; o >>= 1) {
    s  += __shfl_down(s, o, 64);
    sq += __shfl_down(sq, o, 64);
  }
  __shared__ float rs[4], rq[4];
  if ((threadIdx.x & 63) == 0) { rs[threadIdx.x >> 6] = s; rq[threadIdx.x >> 6] = sq; }
  __syncthreads();
  s  = rs[0] + rs[1] + rs[2] + rs[3];
  sq = rq[0] + rq[1] + rq[2] + rq[3];

  const float mean = s * (1.f / DIM);
  const float var  = sq * (1.f / DIM) - mean * mean;
  const float inv  = rsqrtf(var + EPS);

  f32x4 g0 = *(const f32x4*)(gamma + c0);
  f32x4 g1 = *(const f32x4*)(gamma + c0 + 4);
  f32x4 b0 = *(const f32x4*)(beta + c0);
  f32x4 b1 = *(const f32x4*)(beta + c0 + 4);
  #pragma unroll
  for (int r = 0; r < 4; ++r) {
    x0[r] = (x0[r] - mean) * inv * g0[r] + b0[r];
    x1[r] = (x1[r] - mean) * inv * g1[r] + b1[r];
  }
  *(f32x4*)(p + c0)     = x0;
  *(f32x4*)(p + c0 + 4) = x1;
}

// ---------------- attn_w == 1.0 exactly ---------------------------------------
__global__ __launch_bounds__(256) void k_fill_ones(float* __restrict__ p, int n) {
  const int i = blockIdx.x * 256 + threadIdx.x;
  if (i < n) p[i] = 1.0f;
}

extern "C" void kernel_launch(void* const* d_in, const int* in_sizes, int n_in,
                              void* d_out, int out_size, void* d_ws, size_t ws_size,
                              hipStream_t stream) {
  const float* e_a      = (const float*)d_in[0];
  const float* e_b      = (const float*)d_in[1];
  const float* w_in_ab  = (const float*)d_in[2];
  const float* b_in_ab  = (const float*)d_in[3];
  const float* w_out_ab = (const float*)d_in[4];
  const float* b_out_ab = (const float*)d_in[5];
  const float* w_in_ba  = (const float*)d_in[6];
  const float* b_in_ba  = (const float*)d_in[7];
  const float* w_out_ba = (const float*)d_in[8];
  const float* b_out_ba = (const float*)d_in[9];
  const float* gamma_a  = (const float*)d_in[10];
  const float* beta_a   = (const float*)d_in[11];
  const float* gamma_b  = (const float*)d_in[12];
  const float* beta_b   = (const float*)d_in[13];
  float* out = (float*)d_out;

  // Workspace carve-up (~185 MB total).
  char* w = (char*)d_ws;
  bf16_t* eA_bf  = (bf16_t*)w; w += (size_t)B_ROWS * DIM * 2;
  bf16_t* eB_bf  = (bf16_t*)w; w += (size_t)B_ROWS * DIM * 2;
  bf16_t* woAB   = (bf16_t*)w; w += (size_t)DIM * DIM * 2;
  bf16_t* woBA   = (bf16_t*)w; w += (size_t)DIM * DIM * 2;
  bf16_t* wvTAB  = (bf16_t*)w; w += (size_t)DIM * DIM * 2;
  bf16_t* wvTBA  = (bf16_t*)w; w += (size_t)DIM * DIM * 2;
  bf16_t* wcAB   = (bf16_t*)w; w += (size_t)DIM * DIM * 2;
  bf16_t* wcBA   = (bf16_t*)w; w += (size_t)DIM * DIM * 2;
  float*  bcAB   = (float*)w;  w += (size_t)DIM * 4;
  float*  bcBA   = (float*)w;  w += (size_t)DIM * 4;

  const size_t nE = (size_t)B_ROWS * DIM;   // 33,554,432
  const size_t nW = (size_t)DIM * DIM;      // 4,194,304

  // 1) dtype conversions
  k_f32_to_bf16<<<nE / 2048, 256, 0, stream>>>(e_a, eA_bf);
  k_f32_to_bf16<<<nE / 2048, 256, 0, stream>>>(e_b, eB_bf);
  k_f32_to_bf16<<<nW / 2048, 256, 0, stream>>>(w_out_ab, woAB);
  k_f32_to_bf16<<<nW / 2048, 256, 0, stream>>>(w_out_ba, woBA);
  // wv is rows [2D, 3D) of w_in; we need Wv^T (K-contiguous for the combine GEMM)
  k_transpose_bf16<<<dim3(64, 64), 256, 0, stream>>>(w_in_ab + 2 * nW, wvTAB, DIM);
  k_transpose_bf16<<<dim3(64, 64), 256, 0, stream>>>(w_in_ba + 2 * nW, wvTBA, DIM);
  // combined bias (fp32, exact)
  k_bias_combine<<<DIM, 256, 0, stream>>>(w_out_ab, b_in_ab + 2 * DIM, b_out_ab, bcAB, DIM);
  k_bias_combine<<<DIM, 256, 0, stream>>>(w_out_ba, b_in_ba + 2 * DIM, b_out_ba, bcBA, DIM);

  // 2) weight-combine GEMMs: Wc[i,j] = sum_k w_out[i,k] * wv[k,j]
  k_gemm_bt_small<<<dim3(16, 16), 256, 0, stream>>>(woAB, wvTAB, wcAB, DIM, DIM, DIM);
  k_gemm_bt_small<<<dim3(16, 16), 256, 0, stream>>>(woBA, wvTBA, wcBA, DIM, DIM, DIM);

  // 3) main GEMMs with fused residual + bias, fp32 out into d_out
  //    s_a = e_b @ WcAB^T + e_a + bcAB ; s_b = e_a @ WcBA^T + e_b + bcBA
  k_gemm256<<<dim3(8, 64), 512, 0, stream>>>(eB_bf, wcAB, out,      e_a, bcAB,
                                             B_ROWS, DIM, DIM);
  k_gemm256<<<dim3(8, 64), 512, 0, stream>>>(eA_bf, wcBA, out + nE, e_b, bcBA,
                                             B_ROWS, DIM, DIM);

  // 4) in-place LayerNorm on both halves of d_out
  k_ln<<<2 * B_ROWS, 256, 0, stream>>>(out, gamma_a, beta_a, gamma_b, beta_b);

  // 5) attn_w output: exactly 1.0
  k_fill_ones<<<(B_ROWS + 255) / 256, 256, 0, stream>>>(out + 2 * nE, B_ROWS);
}